// Round 1
// baseline (782.330 us; speedup 1.0000x reference)
//
#include <hip/hip_runtime.h>

#define N_VERTICES 1000000
#define N_EDGES    16000000

// Scatter-add edge_attr[e] into acc[src[e]]. Vectorized 4-wide loads;
// atomics target a 4 MB L2/L3-resident array, so contention is cheap.
__global__ void edge_scatter4(const int4* __restrict__ src4,
                              const float4* __restrict__ ea4,
                              float* __restrict__ acc, int ne4) {
    int i = blockIdx.x * blockDim.x + threadIdx.x;
    int stride = gridDim.x * blockDim.x;
    for (; i < ne4; i += stride) {
        int4 s = src4[i];
        float4 v = ea4[i];
        atomicAdd(&acc[s.x], v.x);
        atomicAdd(&acc[s.y], v.y);
        atomicAdd(&acc[s.z], v.z);
        atomicAdd(&acc[s.w], v.w);
    }
}

// Per-vertex epilogue: out[i] = [A_ii, C_i, gammabar_i / A_ii] row-major (N,3).
__global__ void vertex_out(const float2* __restrict__ va,
                           const float* __restrict__ acc,
                           float* __restrict__ out, int nv) {
    int i = blockIdx.x * blockDim.x + threadIdx.x;
    if (i < nv) {
        float2 v = va[i];          // v.x = A_ii, v.y = C_i
        float g = acc[i];
        out[3 * i + 0] = v.x;
        out[3 * i + 1] = v.y;
        out[3 * i + 2] = g / v.x;
    }
}

extern "C" void kernel_launch(void* const* d_in, const int* in_sizes, int n_in,
                              void* d_out, int out_size, void* d_ws, size_t ws_size,
                              hipStream_t stream) {
    const float* vertex_attr = (const float*)d_in[0];   // (N_VERTICES, 2) f32
    const int*   edgeij      = (const int*)d_in[1];     // (2, N_EDGES) int32; row 0 = src
    const float* edge_attr   = (const float*)d_in[2];   // (N_EDGES, 1) f32
    float* out = (float*)d_out;                          // (N_VERTICES, 3) f32
    float* acc = (float*)d_ws;                           // gammabar accumulator

    // Zero the accumulator every call (harness does not re-poison d_ws).
    hipMemsetAsync(acc, 0, N_VERTICES * sizeof(float), stream);

    // Edge scatter: 16M edges, 4-wide, grid-stride over ~2048 blocks.
    int ne4 = N_EDGES / 4;
    int blocks = 2048;
    edge_scatter4<<<blocks, 256, 0, stream>>>(
        (const int4*)edgeij, (const float4*)edge_attr, acc, ne4);

    // Vertex epilogue.
    int vblocks = (N_VERTICES + 255) / 256;
    vertex_out<<<vblocks, 256, 0, stream>>>(
        (const float2*)vertex_attr, acc, out, N_VERTICES);
}